// Round 5
// baseline (1485.138 us; speedup 1.0000x reference)
//
#include <hip/hip_runtime.h>
#include <stdint.h>

// Fused shifted-window attention. B=32, H=W=112, C=128, heads=4, d=32, N=49.
// FP32 global I/O; bf16 MFMA compute, fp32 accumulation.
//
// v2: transpose-free fragment chaining (q^T,k^T swapped W·X^T; v normal) so
//     C-frags feed mfma_16x16x16 directly; S^T = K·Q^T, O^T = V^T·P^T.
// v4: phase order qk -> S/softmax -> v -> PV caps live frags; VGPR 84, 249 us.
// v5: direct scattered stores + LDS alias: regressed (267 us) -- scattered
//     64-B stores + no occupancy gain (VGPR 92 in the 65..128 bucket).
// v6: occupancy attack. Evidence (v1/v4/v5: VGPR 72/84/92 -> same ~33% occ)
//     matches the m68/m69 VGPR quantum: waves/SIMD steps only at 64/128.
//     So: 8 waves/block (2 per head, token-split), live set <= ~52 regs,
//     __launch_bounds__(512,8) -> 64-VGPR budget -> 8 waves/SIMD, 32 waves/CU
//     (2x). k/v GEMMs duplicated per wave pair (+33% MFMA, MFMA is 16% busy).
//     Stores: v4's proven staged+coalesced path (region2), NOT v5's scatter.

typedef __attribute__((ext_vector_type(8))) short short8;          // 8 bf16 (K=32 A/B frag)
typedef __attribute__((ext_vector_type(8))) unsigned short ushort8;
typedef __attribute__((ext_vector_type(4))) short short4v;         // 4 bf16 (K=16 A/B frag)
typedef __attribute__((ext_vector_type(4))) float f32x4;
typedef __attribute__((ext_vector_type(2))) float float2v;
typedef __attribute__((ext_vector_type(2))) unsigned uint2v;
typedef __attribute__((ext_vector_type(2))) __bf16 bf16x2;

#define MFMA32(a, b, c) __builtin_amdgcn_mfma_f32_16x16x32_bf16((a), (b), (c), 0, 0, 0)

#if __has_builtin(__builtin_amdgcn_mfma_f32_16x16x16bf16_1k)
#define MFMA16(a, b, c) __builtin_amdgcn_mfma_f32_16x16x16bf16_1k((a), (b), (c), 0, 0, 0)
#else
__device__ __forceinline__ f32x4 mfma16_fb(short4v a, short4v b, f32x4 c) {
  f32x4 d;
  asm volatile("v_mfma_f32_16x16x16_bf16 %0, %1, %2, %3" : "=v"(d) : "v"(a), "v"(b), "v"(c));
  return d;
}
#define MFMA16(a, b, c) mfma16_fb((a), (b), (c))
#endif

#if __has_builtin(__builtin_amdgcn_exp2f)
#define EXP2F(x) __builtin_amdgcn_exp2f(x)
#else
#define EXP2F(x) __expf(0.6931471805599453f * (x))
#endif

#define LOG2E 1.4426950408889634f
#define SCQ   0.25503486f          // d^-0.5 * log2(e)
#define MASKV 144.26950408889634f  // 100 * log2(e)

// pair fp32 -> packed bf16x2 (RNE); vector fptrunc -> v_cvt_pk_bf16_f32
__device__ __forceinline__ unsigned pk2bf(float a, float b) {
  float2v t; t.x = a; t.y = b;
  return __builtin_bit_cast(unsigned, __builtin_convertvector(t, bf16x2));
}
__device__ __forceinline__ float bf2f(unsigned short h) {
  union { unsigned u; float f; } v; v.u = ((unsigned)h) << 16;
  return v.f;
}
__device__ __forceinline__ short8 ld8(const unsigned short* p) {
  return __builtin_bit_cast(short8, *(const ushort8*)p);
}
__device__ __forceinline__ short4v mk4(unsigned lo, unsigned hi) {
  uint2v u; u.x = lo; u.y = hi;
  return __builtin_bit_cast(short4v, u);
}

// ---- workspace layout (bytes) ----
// bias4 fp32 [4 cls][4 h][16 mt*nt][64 lane] x f32x4 : @0, 262144 B  (S^T orient)
// qkvw bf16 [384][128]  : @262144, 98304 B
// projw bf16 [128][128] : @360448, 32768 B   (total 393216 B)
#define WS_W_OFF 262144

// ================= prologue: weight convert + bias/mask precompute ==========
// bias4 holds log2e*(rel_bias + shift_mask) in the C-layout of S^T:
//   tile (mt = key tile, nt = token tile); lane: col = token nt*16+l16 (clamped
//   to 48), rows = key mt*16+quad*4+r; key > 48 -> -1e30 (exp2 -> 0).
__global__ __launch_bounds__(256, 1)
void prep_kernel(const float* __restrict__ qkvw, const float* __restrict__ projw,
                 const float* __restrict__ tbl,
                 float* __restrict__ bias4, unsigned short* __restrict__ wbf) {
  const int tid = blockIdx.x * 256 + threadIdx.x;
  if (tid < 16384) {
    const int lane = tid & 63;
    const int mtnt = (tid >> 6) & 15;
    const int h    = (tid >> 10) & 3;
    const int cls  = (tid >> 12) & 3;          // (wy==15)*2 + (wx==15)
    const int mt = mtnt >> 2, nt = mtnt & 3;   // mt: key tile, nt: token tile
    const int m0 = mt * 16 + (lane >> 4) * 4;  // key row base
    int n = nt * 16 + (lane & 15);             // token col
    if (n > 48) n = 48;                        // clamp matches clamped B-cols
    const int cy = cls >> 1, cx = cls & 1;
    const int it = n / 7, jt = n - (n / 7) * 7;
    const int rt = (cy ? (it < 4 ? 1 : 2) : 0) * 3 + (cx ? (jt < 4 ? 1 : 2) : 0);
    f32x4 v;
#pragma unroll
    for (int r = 0; r < 4; ++r) {
      const int m = m0 + r;
      if (m > 48) { v[r] = -1.0e30f; continue; }   // pad keys -> exp2 = 0
      const int im = m / 7, jm = m - (m / 7) * 7;
      const int rm = (cy ? (im < 4 ? 1 : 2) : 0) * 3 + (cx ? (jm < 4 ? 1 : 2) : 0);
      const int idx = (it - im + 6) * 13 + (jt - jm + 6);  // bias[query=n][key=m]
      float bv = tbl[idx * 4 + h] * LOG2E;
      if (rm != rt) bv -= MASKV;                 // shift mask (symmetric)
      v[r] = bv;
    }
    *(f32x4*)(bias4 + tid * 4) = v;
  } else {
    const int e = tid - 16384;                   // weight f32x4 chunks
    const float* src; int dst;
    if (e < 12288) { src = qkvw + e * 4;             dst = e * 4; }
    else           { src = projw + (e - 12288) * 4;  dst = 49152 + (e - 12288) * 4; }
    f32x4 a = *(const f32x4*)src;
    uint2v s; s.x = pk2bf(a[0], a[1]); s.y = pk2bf(a[2], a[3]);
    *(uint2v*)(wbf + dst) = s;
  }
}

// ---- LDS (ushort units): region1 xw/O [49][136] @0 (6664 us), region2
// staging [49][136] @6664. Total 13328 us = 26656 B. Occupancy: thread cap
// 4 blocks x 8 waves = 32 waves/CU when VGPR <= 64 (launch_bounds 512,8). ----
__global__ __launch_bounds__(512, 8)
void swin_attn_kernel(const float* __restrict__ x,
                      const float* __restrict__ qkvb,
                      const float* __restrict__ projb,
                      const float* __restrict__ bias4,
                      const unsigned short* __restrict__ wbf,
                      float* __restrict__ out) {
  __shared__ unsigned short sm[13328];
  unsigned short* __restrict__ xw = sm;          // X window, later O [token][128]
  unsigned short* __restrict__ st = sm + 6664;   // proj output staging

  const int t    = threadIdx.x;
  const int lane = t & 63;
  const int wv   = t >> 6;      // wave id 0..7
  const int h    = wv >> 1;     // head 0..3
  const int th   = wv & 1;      // token half 0..1 (nt in {2*th, 2*th+1})
  const int quad = lane >> 4;
  const int l16  = lane & 15;

  const int wid = blockIdx.x;
  const int b   = wid >> 8;     // batch
  const int w   = wid & 255;
  const int wy  = w >> 4;
  const int wx  = w & 15;

  // ---- phase 0: shifted window load (roll folded into index), fp32 -> bf16 ----
  {
    const int c4 = t & 31, pr = t >> 5;   // 16 rows per pass, 512 B per row
#pragma unroll
    for (int p = 0; p < 4; ++p) {
      const int n = p * 16 + pr;
      if (n < 49) {
        const int i = (n * 37) >> 8, j = n - i * 7;
        const int gi = (wy * 7 + i + 3) % 112;
        const int gj = (wx * 7 + j + 3) % 112;
        f32x4 v = *(const f32x4*)(x + ((((long)b * 112 + gi) * 112 + gj) << 7) + c4 * 4);
        uint2v s; s.x = pk2bf(v[0], v[1]); s.y = pk2bf(v[2], v[3]);
        *(uint2v*)&xw[n * 136 + c4 * 4] = s;
      }
    }
  }
  __syncthreads();   // A: xw ready

  // ---- phase 1qk: k FULL (4 token tiles), q for this wave's 2 tiles ----
  // kbf[ft][nt], qbf[ft][j] (j = local tile, global nt = 2*th+j): 2 u32 each.
  unsigned kbf[2][4][2], qbf[2][2][2];
#pragma unroll
  for (int ft = 0; ft < 2; ++ft) {      // k = W_k · X^T (swapped)
    const int wrow = 128 + h * 32 + ft * 16 + l16;
    const unsigned short* wp = wbf + (wrow << 7) + quad * 8;
    const short8 wf0 = ld8(wp), wf1 = ld8(wp + 32), wf2 = ld8(wp + 64), wf3 = ld8(wp + 96);
    const f32x4 bias = *(const f32x4*)(qkvb + 128 + h * 32 + ft * 16 + quad * 4);
#pragma unroll
    for (int nt = 0; nt < 4; ++nt) {
      int ar = nt * 16 + l16; if (ar > 48) ar = 48;       // pad tokens -> row 48
      const unsigned short* ap = &xw[ar * 136 + quad * 8];
      f32x4 acc = {0.f, 0.f, 0.f, 0.f};
      acc = MFMA32(wf0, ld8(ap), acc);
      acc = MFMA32(wf1, ld8(ap + 32), acc);
      acc = MFMA32(wf2, ld8(ap + 64), acc);
      acc = MFMA32(wf3, ld8(ap + 96), acc);
      kbf[ft][nt][0] = pk2bf(acc[0] + bias[0], acc[1] + bias[1]);
      kbf[ft][nt][1] = pk2bf(acc[2] + bias[2], acc[3] + bias[3]);
    }
  }
#pragma unroll
  for (int ft = 0; ft < 2; ++ft) {      // q = W_q · X^T (swapped), half tiles
    const int wrow = h * 32 + ft * 16 + l16;
    const unsigned short* wp = wbf + (wrow << 7) + quad * 8;
    const short8 wf0 = ld8(wp), wf1 = ld8(wp + 32), wf2 = ld8(wp + 64), wf3 = ld8(wp + 96);
    const f32x4 bias = *(const f32x4*)(qkvb + h * 32 + ft * 16 + quad * 4);
#pragma unroll
    for (int j = 0; j < 2; ++j) {
      const int nt = 2 * th + j;
      int ar = nt * 16 + l16; if (ar > 48) ar = 48;
      const unsigned short* ap = &xw[ar * 136 + quad * 8];
      f32x4 acc = {0.f, 0.f, 0.f, 0.f};
      acc = MFMA32(wf0, ld8(ap), acc);
      acc = MFMA32(wf1, ld8(ap + 32), acc);
      acc = MFMA32(wf2, ld8(ap + 64), acc);
      acc = MFMA32(wf3, ld8(ap + 96), acc);
      qbf[ft][j][0] = pk2bf((acc[0] + bias[0]) * SCQ, (acc[1] + bias[1]) * SCQ);
      qbf[ft][j][1] = pk2bf((acc[2] + bias[2]) * SCQ, (acc[3] + bias[3]) * SCQ);
    }
  }

  // ---- phase 2a: S^T = K·Q^T + bias (mfma16), softmax -> packed P ----
  // q/k die after this; pf (16 u32) + inv (2 f32) survive. No max-pass
  // (|scores| small, exact invariance), unnormalized P, 1/sum deferred.
  unsigned pf[2][4][2];
  float inv[2];
  {
    const float* bb = bias4 + ((((wy == 15) * 2 + (wx == 15)) * 4 + h) << 12);
#pragma unroll
    for (int j = 0; j < 2; ++j) {
      const int nt = 2 * th + j;
      float psum = 0.f;
#pragma unroll
      for (int mt = 0; mt < 4; ++mt) {
        f32x4 s = *(const f32x4*)(bb + ((((mt << 2) | nt) << 6) + lane) * 4);
        s = MFMA16(mk4(kbf[0][mt][0], kbf[0][mt][1]), mk4(qbf[0][j][0], qbf[0][j][1]), s);
        s = MFMA16(mk4(kbf[1][mt][0], kbf[1][mt][1]), mk4(qbf[1][j][0], qbf[1][j][1]), s);
        const float e0 = EXP2F(s[0]);
        const float e1 = EXP2F(s[1]);
        const float e2 = EXP2F(s[2]);
        const float e3 = EXP2F(s[3]);
        psum += (e0 + e1) + (e2 + e3);
        pf[j][mt][0] = pk2bf(e0, e1);
        pf[j][mt][1] = pk2bf(e2, e3);
      }
      psum += __shfl_xor(psum, 16);     // token's 64 keys live in 4 lanes
      psum += __shfl_xor(psum, 32);
      inv[j] = 1.0f / psum;
    }
  }

  // ---- phase 1b: v = X · Wv^T FULL (xw still intact; C-frags = V^T A-frags) ----
  unsigned vbf[4][2][2];
#pragma unroll
  for (int dt = 0; dt < 2; ++dt) {
    const int fcol = 256 + h * 32 + dt * 16 + l16;
    const unsigned short* wp = wbf + (fcol << 7) + quad * 8;
    const short8 wf0 = ld8(wp), wf1 = ld8(wp + 32), wf2 = ld8(wp + 64), wf3 = ld8(wp + 96);
    const float bias = qkvb[fcol];
#pragma unroll
    for (int kt = 0; kt < 4; ++kt) {
      int ar = kt * 16 + l16; if (ar > 48) ar = 48;
      const unsigned short* ap = &xw[ar * 136 + quad * 8];
      f32x4 acc = {0.f, 0.f, 0.f, 0.f};
      acc = MFMA32(ld8(ap), wf0, acc);
      acc = MFMA32(ld8(ap + 32), wf1, acc);
      acc = MFMA32(ld8(ap + 64), wf2, acc);
      acc = MFMA32(ld8(ap + 96), wf3, acc);
      vbf[kt][dt][0] = pk2bf(acc[0] + bias, acc[1] + bias);
      vbf[kt][dt][1] = pk2bf(acc[2] + bias, acc[3] + bias);
    }
  }
  __syncthreads();   // B: all xw reads done -> O may overwrite the region

  // ---- phase 2b: O^T = V^T · P^T; 4 consecutive features -> 8B packed write ----
#pragma unroll
  for (int j = 0; j < 2; ++j) {
    const int token = (2 * th + j) * 16 + l16;
#pragma unroll
    for (int dt = 0; dt < 2; ++dt) {
      f32x4 o = {0.f, 0.f, 0.f, 0.f};
#pragma unroll
      for (int mt = 0; mt < 4; ++mt)
        o = MFMA16(mk4(vbf[mt][dt][0], vbf[mt][dt][1]), mk4(pf[j][mt][0], pf[j][mt][1]), o);
      if (token < 49) {
        uint2v pkd;
        pkd.x = pk2bf(o[0] * inv[j], o[1] * inv[j]);
        pkd.y = pk2bf(o[2] * inv[j], o[3] * inv[j]);
        *(uint2v*)&xw[token * 136 + h * 32 + dt * 16 + quad * 4] = pkd;
      }
    }
  }
  __syncthreads();   // C: all heads' O ready

  // ---- phase 3: proj swapped (out^T = Wp · O^T), one 16-feature tile/wave;
  // stage bf16 into region2 (coalesced store path proven in v4) ----
  {
    const int mtile = wv;             // 8 waves x 16 features = 128
    const unsigned short* wp = wbf + 49152 + ((mtile * 16 + l16) << 7) + quad * 8;
    const short8 wf0 = ld8(wp), wf1 = ld8(wp + 32), wf2 = ld8(wp + 64), wf3 = ld8(wp + 96);
    const f32x4 bias = *(const f32x4*)(projb + mtile * 16 + quad * 4);
#pragma unroll
    for (int nt = 0; nt < 4; ++nt) {
      int ar = nt * 16 + l16; if (ar > 48) ar = 48;
      const unsigned short* op = &xw[ar * 136 + quad * 8];
      f32x4 acc = {0.f, 0.f, 0.f, 0.f};
      acc = MFMA32(wf0, ld8(op), acc);
      acc = MFMA32(wf1, ld8(op + 32), acc);
      acc = MFMA32(wf2, ld8(op + 64), acc);
      acc = MFMA32(wf3, ld8(op + 96), acc);
      const int token = nt * 16 + l16;
      if (token < 49) {
        uint2v pkd;
        pkd.x = pk2bf(acc[0] + bias[0], acc[1] + bias[1]);
        pkd.y = pk2bf(acc[2] + bias[2], acc[3] + bias[3]);
        *(uint2v*)&st[token * 136 + mtile * 16 + quad * 4] = pkd;
      }
    }
  }
  __syncthreads();   // E: staging ready

  // ---- phase 4: coalesced fp32 store (inverse roll == same index mapping) ----
  {
    const int c4 = t & 31, pr = t >> 5;
#pragma unroll
    for (int p = 0; p < 4; ++p) {
      const int n = p * 16 + pr;
      if (n < 49) {
        const int i = (n * 37) >> 8, j = n - i * 7;
        const int gi = (wy * 7 + i + 3) % 112;
        const int gj = (wx * 7 + j + 3) % 112;
        uint2v s = *(const uint2v*)&st[n * 136 + c4 * 4];
        f32x4 v;
        v[0] = bf2f((unsigned short)(s.x & 0xFFFFu));
        v[1] = bf2f((unsigned short)(s.x >> 16));
        v[2] = bf2f((unsigned short)(s.y & 0xFFFFu));
        v[3] = bf2f((unsigned short)(s.y >> 16));
        *(f32x4*)(out + ((((long)b * 112 + gi) * 112 + gj) << 7) + c4 * 4) = v;
      }
    }
  }
}

extern "C" void kernel_launch(void* const* d_in, const int* in_sizes, int n_in,
                              void* d_out, int out_size, void* d_ws, size_t ws_size,
                              hipStream_t stream) {
  (void)in_sizes; (void)n_in; (void)out_size; (void)ws_size;
  const float* x     = (const float*)d_in[0];
  const float* qkvw  = (const float*)d_in[1];
  const float* qkvb  = (const float*)d_in[2];
  const float* projw = (const float*)d_in[3];
  const float* projb = (const float*)d_in[4];
  const float* tbl   = (const float*)d_in[5];
  float* outp = (float*)d_out;

  float*          ws_bias = (float*)d_ws;
  unsigned short* ws_w    = (unsigned short*)((char*)d_ws + WS_W_OFF);

  prep_kernel<<<128, 256, 0, stream>>>(qkvw, projw, tbl, ws_bias, ws_w);
  // main: 32 batches * 256 windows, 8 waves (2 per head) each
  swin_attn_kernel<<<8192, 512, 0, stream>>>(x, qkvb, projb, ws_bias, ws_w, outp);
}

// Round 6
// 590.799 us; speedup vs baseline: 2.5138x; 2.5138x over previous
//
#include <hip/hip_runtime.h>
#include <stdint.h>

// Fused shifted-window attention. B=32, H=W=112, C=128, heads=4, d=32, N=49.
// FP32 global I/O; bf16 MFMA compute, fp32 accumulation.
//
// v2: transpose-free fragment chaining (q^T,k^T swapped W·X^T; v normal) so
//     C-frags feed mfma_16x16x16 directly; S^T = K·Q^T, O^T = V^T·P^T.
// v4: phase order qk -> S/softmax -> v -> PV; VGPR 84 @ (256,2), 249 us, occ 33%.
// v5: scattered direct stores: regressed (267 us).
// v6: (512,8): allocator capped at 32 arch VGPRs -> 5.1 GB spill, 1260 us.
//     LAW: declared min-waves caps arch VGPRs (~256*2/minw for 256-thr);
//     demand above cap = scratch spill. Occupancy buckets at VGPR 64/128.
// v7: make natural demand <= 64, then declare (256,4):
//     k GEMM (16 persistent) + v GEMM (16 persistent), then PER-TOKEN-TILE
//     loop {q GEMM (4) -> S+exp -> pf (8, dies) -> PV -> O to LDS region2}.
//     Peak ~60 regs. proj stages into region1 (v4's coalesced store path).
//     LDS 26656 B -> 6 blocks/CU = 24 waves/CU (vs 16).

typedef __attribute__((ext_vector_type(8))) short short8;          // 8 bf16 (K=32 A/B frag)
typedef __attribute__((ext_vector_type(8))) unsigned short ushort8;
typedef __attribute__((ext_vector_type(4))) short short4v;         // 4 bf16 (K=16 A/B frag)
typedef __attribute__((ext_vector_type(4))) float f32x4;
typedef __attribute__((ext_vector_type(2))) float float2v;
typedef __attribute__((ext_vector_type(2))) unsigned uint2v;
typedef __attribute__((ext_vector_type(2))) __bf16 bf16x2;

#define MFMA32(a, b, c) __builtin_amdgcn_mfma_f32_16x16x32_bf16((a), (b), (c), 0, 0, 0)

#if __has_builtin(__builtin_amdgcn_mfma_f32_16x16x16bf16_1k)
#define MFMA16(a, b, c) __builtin_amdgcn_mfma_f32_16x16x16bf16_1k((a), (b), (c), 0, 0, 0)
#else
__device__ __forceinline__ f32x4 mfma16_fb(short4v a, short4v b, f32x4 c) {
  f32x4 d;
  asm volatile("v_mfma_f32_16x16x16_bf16 %0, %1, %2, %3" : "=v"(d) : "v"(a), "v"(b), "v"(c));
  return d;
}
#define MFMA16(a, b, c) mfma16_fb((a), (b), (c))
#endif

#if __has_builtin(__builtin_amdgcn_exp2f)
#define EXP2F(x) __builtin_amdgcn_exp2f(x)
#else
#define EXP2F(x) __expf(0.6931471805599453f * (x))
#endif

#define LOG2E 1.4426950408889634f
#define SCQ   0.25503486f          // d^-0.5 * log2(e)
#define MASKV 144.26950408889634f  // 100 * log2(e)

// pair fp32 -> packed bf16x2 (RNE); vector fptrunc -> v_cvt_pk_bf16_f32
__device__ __forceinline__ unsigned pk2bf(float a, float b) {
  float2v t; t.x = a; t.y = b;
  return __builtin_bit_cast(unsigned, __builtin_convertvector(t, bf16x2));
}
__device__ __forceinline__ float bf2f(unsigned short h) {
  union { unsigned u; float f; } v; v.u = ((unsigned)h) << 16;
  return v.f;
}
__device__ __forceinline__ short8 ld8(const unsigned short* p) {
  return __builtin_bit_cast(short8, *(const ushort8*)p);
}
__device__ __forceinline__ short4v mk4(unsigned lo, unsigned hi) {
  uint2v u; u.x = lo; u.y = hi;
  return __builtin_bit_cast(short4v, u);
}

// ---- workspace layout (bytes) ----
// bias4 fp32 [4 cls][4 h][16 mt*nt][64 lane] x f32x4 : @0, 262144 B  (S^T orient)
// qkvw bf16 [384][128]  : @262144, 98304 B
// projw bf16 [128][128] : @360448, 32768 B   (total 393216 B)
#define WS_W_OFF 262144

// ================= prologue: weight convert + bias/mask precompute ==========
// bias4 holds log2e*(rel_bias + shift_mask) in the C-layout of S^T:
//   tile (mt = key tile, nt = token tile); lane: col = token nt*16+l16 (clamped
//   to 48), rows = key mt*16+quad*4+r; key > 48 -> -1e30 (exp2 -> 0).
__global__ __launch_bounds__(256, 1)
void prep_kernel(const float* __restrict__ qkvw, const float* __restrict__ projw,
                 const float* __restrict__ tbl,
                 float* __restrict__ bias4, unsigned short* __restrict__ wbf) {
  const int tid = blockIdx.x * 256 + threadIdx.x;
  if (tid < 16384) {
    const int lane = tid & 63;
    const int mtnt = (tid >> 6) & 15;
    const int h    = (tid >> 10) & 3;
    const int cls  = (tid >> 12) & 3;          // (wy==15)*2 + (wx==15)
    const int mt = mtnt >> 2, nt = mtnt & 3;   // mt: key tile, nt: token tile
    const int m0 = mt * 16 + (lane >> 4) * 4;  // key row base
    int n = nt * 16 + (lane & 15);             // token col
    if (n > 48) n = 48;                        // clamp matches clamped B-cols
    const int cy = cls >> 1, cx = cls & 1;
    const int it = n / 7, jt = n - (n / 7) * 7;
    const int rt = (cy ? (it < 4 ? 1 : 2) : 0) * 3 + (cx ? (jt < 4 ? 1 : 2) : 0);
    f32x4 v;
#pragma unroll
    for (int r = 0; r < 4; ++r) {
      const int m = m0 + r;
      if (m > 48) { v[r] = -1.0e30f; continue; }   // pad keys -> exp2 = 0
      const int im = m / 7, jm = m - (m / 7) * 7;
      const int rm = (cy ? (im < 4 ? 1 : 2) : 0) * 3 + (cx ? (jm < 4 ? 1 : 2) : 0);
      const int idx = (it - im + 6) * 13 + (jt - jm + 6);  // bias[query=n][key=m]
      float bv = tbl[idx * 4 + h] * LOG2E;
      if (rm != rt) bv -= MASKV;                 // shift mask (symmetric)
      v[r] = bv;
    }
    *(f32x4*)(bias4 + tid * 4) = v;
  } else {
    const int e = tid - 16384;                   // weight f32x4 chunks
    const float* src; int dst;
    if (e < 12288) { src = qkvw + e * 4;             dst = e * 4; }
    else           { src = projw + (e - 12288) * 4;  dst = 49152 + (e - 12288) * 4; }
    f32x4 a = *(const f32x4*)src;
    uint2v s; s.x = pk2bf(a[0], a[1]); s.y = pk2bf(a[2], a[3]);
    *(uint2v*)(wbf + dst) = s;
  }
}

// ---- LDS (ushort units): region1 xw/staging [49][136] @0 (6664 us),
// region2 ob (O [token][128]) [49][136] @6664. Total 13328 us = 26656 B.
// 6 blocks/CU by LDS; VGPR <= 64 (launch_bounds 256,4) -> not binding. ----
__global__ __launch_bounds__(256, 4)
void swin_attn_kernel(const float* __restrict__ x,
                      const float* __restrict__ qkvb,
                      const float* __restrict__ projb,
                      const float* __restrict__ bias4,
                      const unsigned short* __restrict__ wbf,
                      float* __restrict__ out) {
  __shared__ unsigned short sm[13328];
  unsigned short* __restrict__ xw = sm;          // X window, later proj staging
  unsigned short* __restrict__ ob = sm + 6664;   // O [token][128] (+8 pad)

  const int t    = threadIdx.x;
  const int lane = t & 63;
  const int wv   = t >> 6;      // wave id 0..3 == head
  const int quad = lane >> 4;
  const int l16  = lane & 15;

  const int wid = blockIdx.x;
  const int b   = wid >> 8;     // batch
  const int w   = wid & 255;
  const int wy  = w >> 4;
  const int wx  = w & 15;

  // ---- phase 0: shifted window load (roll folded into index), fp32 -> bf16 ----
  {
    const int c4 = t & 31, pr = t >> 5;
#pragma unroll
    for (int p = 0; p < 7; ++p) {
      const int n = p * 8 + pr;
      if (n < 49) {
        const int i = (n * 37) >> 8, j = n - i * 7;
        const int gi = (wy * 7 + i + 3) % 112;
        const int gj = (wx * 7 + j + 3) % 112;
        f32x4 v = *(const f32x4*)(x + ((((long)b * 112 + gi) * 112 + gj) << 7) + c4 * 4);
        uint2v s; s.x = pk2bf(v[0], v[1]); s.y = pk2bf(v[2], v[3]);
        *(uint2v*)&xw[n * 136 + c4 * 4] = s;
      }
    }
  }
  __syncthreads();   // A: xw ready

  // ---- phase 1: k^T = W_k · X^T (swapped), FULL; kbf[ft][mt] persistent ----
  unsigned kbf[2][4][2];
#pragma unroll
  for (int ft = 0; ft < 2; ++ft) {
    const int wrow = 128 + wv * 32 + ft * 16 + l16;
    const unsigned short* wp = wbf + (wrow << 7) + quad * 8;
    const short8 wf0 = ld8(wp), wf1 = ld8(wp + 32), wf2 = ld8(wp + 64), wf3 = ld8(wp + 96);
    const f32x4 bias = *(const f32x4*)(qkvb + 128 + wv * 32 + ft * 16 + quad * 4);
#pragma unroll
    for (int mt = 0; mt < 4; ++mt) {
      int ar = mt * 16 + l16; if (ar > 48) ar = 48;       // pad tokens -> row 48
      const unsigned short* ap = &xw[ar * 136 + quad * 8];
      f32x4 acc = {0.f, 0.f, 0.f, 0.f};
      acc = MFMA32(wf0, ld8(ap), acc);
      acc = MFMA32(wf1, ld8(ap + 32), acc);
      acc = MFMA32(wf2, ld8(ap + 64), acc);
      acc = MFMA32(wf3, ld8(ap + 96), acc);
      kbf[ft][mt][0] = pk2bf(acc[0] + bias[0], acc[1] + bias[1]);
      kbf[ft][mt][1] = pk2bf(acc[2] + bias[2], acc[3] + bias[3]);
    }
  }

  // ---- phase 2: v = X · Wv^T (normal), FULL; vbf[kt][dt] persistent ----
  unsigned vbf[4][2][2];
#pragma unroll
  for (int dt = 0; dt < 2; ++dt) {
    const int fcol = 256 + wv * 32 + dt * 16 + l16;
    const unsigned short* wp = wbf + (fcol << 7) + quad * 8;
    const short8 wf0 = ld8(wp), wf1 = ld8(wp + 32), wf2 = ld8(wp + 64), wf3 = ld8(wp + 96);
    const float bias = qkvb[fcol];
#pragma unroll
    for (int kt = 0; kt < 4; ++kt) {
      int ar = kt * 16 + l16; if (ar > 48) ar = 48;
      const unsigned short* ap = &xw[ar * 136 + quad * 8];
      f32x4 acc = {0.f, 0.f, 0.f, 0.f};
      acc = MFMA32(ld8(ap), wf0, acc);
      acc = MFMA32(ld8(ap + 32), wf1, acc);
      acc = MFMA32(ld8(ap + 64), wf2, acc);
      acc = MFMA32(ld8(ap + 96), wf3, acc);
      vbf[kt][dt][0] = pk2bf(acc[0] + bias, acc[1] + bias);
      vbf[kt][dt][1] = pk2bf(acc[2] + bias, acc[3] + bias);
    }
  }

  // ---- phase 3: per token-tile pipeline: q -> S^T+softmax -> PV -> O ----
  // Transients per nt: qx (4 u32), pf (8 u32), all dead at loop end.
  {
    const float* bb = bias4 + ((((wy == 15) * 2 + (wx == 15)) * 4 + wv) << 12);
#pragma unroll
    for (int nt = 0; nt < 4; ++nt) {
      // q^T = W_q · X^T for this token tile only (xw still intact)
      unsigned qx[2][2];
      {
        int ar = nt * 16 + l16; if (ar > 48) ar = 48;
        const unsigned short* ap = &xw[ar * 136 + quad * 8];
        const short8 a0 = ld8(ap), a1 = ld8(ap + 32), a2 = ld8(ap + 64), a3 = ld8(ap + 96);
#pragma unroll
        for (int ft = 0; ft < 2; ++ft) {
          const int wrow = wv * 32 + ft * 16 + l16;
          const unsigned short* wp = wbf + (wrow << 7) + quad * 8;
          const f32x4 bias = *(const f32x4*)(qkvb + wv * 32 + ft * 16 + quad * 4);
          f32x4 acc = {0.f, 0.f, 0.f, 0.f};
          acc = MFMA32(ld8(wp), a0, acc);
          acc = MFMA32(ld8(wp + 32), a1, acc);
          acc = MFMA32(ld8(wp + 64), a2, acc);
          acc = MFMA32(ld8(wp + 96), a3, acc);
          qx[ft][0] = pk2bf((acc[0] + bias[0]) * SCQ, (acc[1] + bias[1]) * SCQ);
          qx[ft][1] = pk2bf((acc[2] + bias[2]) * SCQ, (acc[3] + bias[3]) * SCQ);
        }
      }
      // S^T = K·Q^T + bias (mfma16), exp2 -> packed P (unnormalized; no
      // max-pass: |scores| small, exact invariance; 1/sum deferred)
      unsigned pf[4][2];
      float psum = 0.f;
#pragma unroll
      for (int mt = 0; mt < 4; ++mt) {
        f32x4 s = *(const f32x4*)(bb + ((((mt << 2) | nt) << 6) + lane) * 4);
        s = MFMA16(mk4(kbf[0][mt][0], kbf[0][mt][1]), mk4(qx[0][0], qx[0][1]), s);
        s = MFMA16(mk4(kbf[1][mt][0], kbf[1][mt][1]), mk4(qx[1][0], qx[1][1]), s);
        const float e0 = EXP2F(s[0]);
        const float e1 = EXP2F(s[1]);
        const float e2 = EXP2F(s[2]);
        const float e3 = EXP2F(s[3]);
        psum += (e0 + e1) + (e2 + e3);
        pf[mt][0] = pk2bf(e0, e1);
        pf[mt][1] = pk2bf(e2, e3);
      }
      psum += __shfl_xor(psum, 16);     // token's 64 keys live in 4 lanes
      psum += __shfl_xor(psum, 32);
      const float inv = 1.0f / psum;
      // O^T = V^T · P^T; 4 consecutive features -> 8B packed write to ob
      const int token = nt * 16 + l16;
#pragma unroll
      for (int dt = 0; dt < 2; ++dt) {
        f32x4 o = {0.f, 0.f, 0.f, 0.f};
#pragma unroll
        for (int mt = 0; mt < 4; ++mt)
          o = MFMA16(mk4(vbf[mt][dt][0], vbf[mt][dt][1]), mk4(pf[mt][0], pf[mt][1]), o);
        if (token < 49) {
          uint2v pkd;
          pkd.x = pk2bf(o[0] * inv, o[1] * inv);
          pkd.y = pk2bf(o[2] * inv, o[3] * inv);
          *(uint2v*)&ob[token * 136 + wv * 32 + dt * 16 + quad * 4] = pkd;
        }
      }
    }
  }
  __syncthreads();   // C: all heads' O ready; all xw reads done

  // ---- phase 4: proj swapped (out^T = Wp · O^T); stage into region1 ----
#pragma unroll
  for (int sub = 0; sub < 2; ++sub) {
    const int mtile = wv * 2 + sub;   // out-feature tile
    const unsigned short* wp = wbf + 49152 + ((mtile * 16 + l16) << 7) + quad * 8;
    const short8 wf0 = ld8(wp), wf1 = ld8(wp + 32), wf2 = ld8(wp + 64), wf3 = ld8(wp + 96);
    const f32x4 bias = *(const f32x4*)(projb + mtile * 16 + quad * 4);
#pragma unroll
    for (int nt = 0; nt < 4; ++nt) {
      int ar = nt * 16 + l16; if (ar > 48) ar = 48;
      const unsigned short* op = &ob[ar * 136 + quad * 8];
      f32x4 acc = {0.f, 0.f, 0.f, 0.f};
      acc = MFMA32(wf0, ld8(op), acc);
      acc = MFMA32(wf1, ld8(op + 32), acc);
      acc = MFMA32(wf2, ld8(op + 64), acc);
      acc = MFMA32(wf3, ld8(op + 96), acc);
      const int token = nt * 16 + l16;
      if (token < 49) {
        uint2v pkd;
        pkd.x = pk2bf(acc[0] + bias[0], acc[1] + bias[1]);
        pkd.y = pk2bf(acc[2] + bias[2], acc[3] + bias[3]);
        *(uint2v*)&xw[token * 136 + mtile * 16 + quad * 4] = pkd;
      }
    }
  }
  __syncthreads();   // E: staging ready

  // ---- phase 5: coalesced fp32 store (inverse roll == same index mapping) ----
  {
    const int c4 = t & 31, pr = t >> 5;
#pragma unroll
    for (int p = 0; p < 7; ++p) {
      const int n = p * 8 + pr;
      if (n < 49) {
        const int i = (n * 37) >> 8, j = n - i * 7;
        const int gi = (wy * 7 + i + 3) % 112;
        const int gj = (wx * 7 + j + 3) % 112;
        uint2v s = *(const uint2v*)&xw[n * 136 + c4 * 4];
        f32x4 v;
        v[0] = bf2f((unsigned short)(s.x & 0xFFFFu));
        v[1] = bf2f((unsigned short)(s.x >> 16));
        v[2] = bf2f((unsigned short)(s.y & 0xFFFFu));
        v[3] = bf2f((unsigned short)(s.y >> 16));
        *(f32x4*)(out + ((((long)b * 112 + gi) * 112 + gj) << 7) + c4 * 4) = v;
      }
    }
  }
}

extern "C" void kernel_launch(void* const* d_in, const int* in_sizes, int n_in,
                              void* d_out, int out_size, void* d_ws, size_t ws_size,
                              hipStream_t stream) {
  (void)in_sizes; (void)n_in; (void)out_size; (void)ws_size;
  const float* x     = (const float*)d_in[0];
  const float* qkvw  = (const float*)d_in[1];
  const float* qkvb  = (const float*)d_in[2];
  const float* projw = (const float*)d_in[3];
  const float* projb = (const float*)d_in[4];
  const float* tbl   = (const float*)d_in[5];
  float* outp = (float*)d_out;

  float*          ws_bias = (float*)d_ws;
  unsigned short* ws_w    = (unsigned short*)((char*)d_ws + WS_W_OFF);

  prep_kernel<<<128, 256, 0, stream>>>(qkvw, projw, tbl, ws_bias, ws_w);
  // main: 32 batches * 256 windows, 4 waves (1 per head) each
  swin_attn_kernel<<<8192, 256, 0, stream>>>(x, qkvb, projb, ws_bias, ws_w, outp);
}

// Round 7
// 517.038 us; speedup vs baseline: 2.8724x; 1.1427x over previous
//
#include <hip/hip_runtime.h>
#include <stdint.h>

// Fused shifted-window attention. B=32, H=W=112, C=128, heads=4, d=32, N=49.
// FP32 global I/O; bf16 MFMA compute, fp32 accumulation.
//
// v2: transpose-free fragment chaining (q^T,k^T swapped W·X^T; v normal) so
//     C-frags feed mfma_16x16x16 directly; S^T = K·Q^T, O^T = V^T·P^T.
// v4: (256,2) -> VGPR 84, no spill, 249 us, occ 33%.
// v6: (512,8) -> cap 32, huge spill. LAW: VGPR cap = 256/min_waves.
// v7: (256,4) -> cap 64, demand ~76 -> 12-dword spill in the hot loop, 370 us
//     BUT occupancy 33->46.5%: the occupancy mechanism works; fit failed.
// v8: get demand <= 64: park the q tiles in LDS (ob region, each wave's own
//     32-col slice, rows nt*16+l16 -- the exact bytes its O write overwrites
//     at the END of iteration nt; in-wave read-before-write, col-disjoint
//     across waves -> no barrier, no extra LDS region). Phase order
//     k -> v -> q(store) -> per-nt loop (q load b128, S, PV, O). Every
//     phase peak ~52-60 regs. ob -> [64][136]; LDS 30736 B, 5 blocks/CU.

typedef __attribute__((ext_vector_type(8))) short short8;          // 8 bf16 (K=32 A/B frag)
typedef __attribute__((ext_vector_type(8))) unsigned short ushort8;
typedef __attribute__((ext_vector_type(4))) short short4v;         // 4 bf16 (K=16 A/B frag)
typedef __attribute__((ext_vector_type(4))) float f32x4;
typedef __attribute__((ext_vector_type(2))) float float2v;
typedef __attribute__((ext_vector_type(2))) unsigned uint2v;
typedef __attribute__((ext_vector_type(4))) unsigned uint4v;
typedef __attribute__((ext_vector_type(2))) __bf16 bf16x2;

#define MFMA32(a, b, c) __builtin_amdgcn_mfma_f32_16x16x32_bf16((a), (b), (c), 0, 0, 0)

#if __has_builtin(__builtin_amdgcn_mfma_f32_16x16x16bf16_1k)
#define MFMA16(a, b, c) __builtin_amdgcn_mfma_f32_16x16x16bf16_1k((a), (b), (c), 0, 0, 0)
#else
__device__ __forceinline__ f32x4 mfma16_fb(short4v a, short4v b, f32x4 c) {
  f32x4 d;
  asm volatile("v_mfma_f32_16x16x16_bf16 %0, %1, %2, %3" : "=v"(d) : "v"(a), "v"(b), "v"(c));
  return d;
}
#define MFMA16(a, b, c) mfma16_fb((a), (b), (c))
#endif

#if __has_builtin(__builtin_amdgcn_exp2f)
#define EXP2F(x) __builtin_amdgcn_exp2f(x)
#else
#define EXP2F(x) __expf(0.6931471805599453f * (x))
#endif

#define LOG2E 1.4426950408889634f
#define SCQ   0.25503486f          // d^-0.5 * log2(e)
#define MASKV 144.26950408889634f  // 100 * log2(e)

// pair fp32 -> packed bf16x2 (RNE); vector fptrunc -> v_cvt_pk_bf16_f32
__device__ __forceinline__ unsigned pk2bf(float a, float b) {
  float2v t; t.x = a; t.y = b;
  return __builtin_bit_cast(unsigned, __builtin_convertvector(t, bf16x2));
}
__device__ __forceinline__ float bf2f(unsigned short h) {
  union { unsigned u; float f; } v; v.u = ((unsigned)h) << 16;
  return v.f;
}
__device__ __forceinline__ short8 ld8(const unsigned short* p) {
  return __builtin_bit_cast(short8, *(const ushort8*)p);
}
__device__ __forceinline__ short4v mk4(unsigned lo, unsigned hi) {
  uint2v u; u.x = lo; u.y = hi;
  return __builtin_bit_cast(short4v, u);
}

// ---- workspace layout (bytes) ----
// bias4 fp32 [4 cls][4 h][16 mt*nt][64 lane] x f32x4 : @0, 262144 B  (S^T orient)
// qkvw bf16 [384][128]  : @262144, 98304 B
// projw bf16 [128][128] : @360448, 32768 B   (total 393216 B)
#define WS_W_OFF 262144

// ================= prologue: weight convert + bias/mask precompute ==========
__global__ __launch_bounds__(256, 1)
void prep_kernel(const float* __restrict__ qkvw, const float* __restrict__ projw,
                 const float* __restrict__ tbl,
                 float* __restrict__ bias4, unsigned short* __restrict__ wbf) {
  const int tid = blockIdx.x * 256 + threadIdx.x;
  if (tid < 16384) {
    const int lane = tid & 63;
    const int mtnt = (tid >> 6) & 15;
    const int h    = (tid >> 10) & 3;
    const int cls  = (tid >> 12) & 3;          // (wy==15)*2 + (wx==15)
    const int mt = mtnt >> 2, nt = mtnt & 3;   // mt: key tile, nt: token tile
    const int m0 = mt * 16 + (lane >> 4) * 4;  // key row base
    int n = nt * 16 + (lane & 15);             // token col
    if (n > 48) n = 48;                        // clamp matches clamped B-cols
    const int cy = cls >> 1, cx = cls & 1;
    const int it = n / 7, jt = n - (n / 7) * 7;
    const int rt = (cy ? (it < 4 ? 1 : 2) : 0) * 3 + (cx ? (jt < 4 ? 1 : 2) : 0);
    f32x4 v;
#pragma unroll
    for (int r = 0; r < 4; ++r) {
      const int m = m0 + r;
      if (m > 48) { v[r] = -1.0e30f; continue; }   // pad keys -> exp2 = 0
      const int im = m / 7, jm = m - (m / 7) * 7;
      const int rm = (cy ? (im < 4 ? 1 : 2) : 0) * 3 + (cx ? (jm < 4 ? 1 : 2) : 0);
      const int idx = (it - im + 6) * 13 + (jt - jm + 6);  // bias[query=n][key=m]
      float bv = tbl[idx * 4 + h] * LOG2E;
      if (rm != rt) bv -= MASKV;                 // shift mask (symmetric)
      v[r] = bv;
    }
    *(f32x4*)(bias4 + tid * 4) = v;
  } else {
    const int e = tid - 16384;                   // weight f32x4 chunks
    const float* src; int dst;
    if (e < 12288) { src = qkvw + e * 4;             dst = e * 4; }
    else           { src = projw + (e - 12288) * 4;  dst = 49152 + (e - 12288) * 4; }
    f32x4 a = *(const f32x4*)src;
    uint2v s; s.x = pk2bf(a[0], a[1]); s.y = pk2bf(a[2], a[3]);
    *(uint2v*)(wbf + dst) = s;
  }
}

// ---- LDS (ushort units): xw/staging [49][136] @0 (6664 us),
// ob [64][136] @6664 (8704 us; q-park rows 0..63, O rows 0..48).
// Total 15368 us = 30736 B -> 5 blocks/CU; VGPR 64 -> 8 waves/SIMD capable. ----
__global__ __launch_bounds__(256, 4)
void swin_attn_kernel(const float* __restrict__ x,
                      const float* __restrict__ qkvb,
                      const float* __restrict__ projb,
                      const float* __restrict__ bias4,
                      const unsigned short* __restrict__ wbf,
                      float* __restrict__ out) {
  __shared__ unsigned short sm[15368];
  unsigned short* __restrict__ xw = sm;          // X window, later proj staging
  unsigned short* __restrict__ ob = sm + 6664;   // q-park, then O [token][128]

  const int t    = threadIdx.x;
  const int lane = t & 63;
  const int wv   = t >> 6;      // wave id 0..3 == head
  const int quad = lane >> 4;
  const int l16  = lane & 15;

  const int wid = blockIdx.x;
  const int b   = wid >> 8;     // batch
  const int w   = wid & 255;
  const int wy  = w >> 4;
  const int wx  = w & 15;

  // ---- phase 0: shifted window load (roll folded into index), fp32 -> bf16 ----
  {
    const int c4 = t & 31, pr = t >> 5;
#pragma unroll
    for (int p = 0; p < 7; ++p) {
      const int n = p * 8 + pr;
      if (n < 49) {
        const int i = (n * 37) >> 8, j = n - i * 7;
        const int gi = (wy * 7 + i + 3) % 112;
        const int gj = (wx * 7 + j + 3) % 112;
        f32x4 v = *(const f32x4*)(x + ((((long)b * 112 + gi) * 112 + gj) << 7) + c4 * 4);
        uint2v s; s.x = pk2bf(v[0], v[1]); s.y = pk2bf(v[2], v[3]);
        *(uint2v*)&xw[n * 136 + c4 * 4] = s;
      }
    }
  }
  __syncthreads();   // A: xw ready

  // ---- phase 1: k^T = W_k · X^T (swapped); kbf[ft][mt] persistent (16) ----
  unsigned kbf[2][4][2];
#pragma unroll
  for (int ft = 0; ft < 2; ++ft) {
    const int wrow = 128 + wv * 32 + ft * 16 + l16;
    const unsigned short* wp = wbf + (wrow << 7) + quad * 8;
    const short8 wf0 = ld8(wp), wf1 = ld8(wp + 32), wf2 = ld8(wp + 64), wf3 = ld8(wp + 96);
    const f32x4 bias = *(const f32x4*)(qkvb + 128 + wv * 32 + ft * 16 + quad * 4);
#pragma unroll
    for (int mt = 0; mt < 4; ++mt) {
      int ar = mt * 16 + l16; if (ar > 48) ar = 48;       // pad tokens -> row 48
      const unsigned short* ap = &xw[ar * 136 + quad * 8];
      f32x4 acc = {0.f, 0.f, 0.f, 0.f};
      acc = MFMA32(wf0, ld8(ap), acc);
      acc = MFMA32(wf1, ld8(ap + 32), acc);
      acc = MFMA32(wf2, ld8(ap + 64), acc);
      acc = MFMA32(wf3, ld8(ap + 96), acc);
      kbf[ft][mt][0] = pk2bf(acc[0] + bias[0], acc[1] + bias[1]);
      kbf[ft][mt][1] = pk2bf(acc[2] + bias[2], acc[3] + bias[3]);
    }
  }

  // ---- phase 2: v = X · Wv^T (normal); vbf[kt][dt] persistent (16) ----
  unsigned vbf[4][2][2];
#pragma unroll
  for (int dt = 0; dt < 2; ++dt) {
    const int fcol = 256 + wv * 32 + dt * 16 + l16;
    const unsigned short* wp = wbf + (fcol << 7) + quad * 8;
    const short8 wf0 = ld8(wp), wf1 = ld8(wp + 32), wf2 = ld8(wp + 64), wf3 = ld8(wp + 96);
    const float bias = qkvb[fcol];
#pragma unroll
    for (int kt = 0; kt < 4; ++kt) {
      int ar = kt * 16 + l16; if (ar > 48) ar = 48;
      const unsigned short* ap = &xw[ar * 136 + quad * 8];
      f32x4 acc = {0.f, 0.f, 0.f, 0.f};
      acc = MFMA32(ld8(ap), wf0, acc);
      acc = MFMA32(ld8(ap + 32), wf1, acc);
      acc = MFMA32(ld8(ap + 64), wf2, acc);
      acc = MFMA32(ld8(ap + 96), wf3, acc);
      vbf[kt][dt][0] = pk2bf(acc[0] + bias, acc[1] + bias);
      vbf[kt][dt][1] = pk2bf(acc[2] + bias, acc[3] + bias);
    }
  }

  // ---- phase 3: q^T = W_q · X^T for all nt, parked into ob (own col slice).
  // Row nt*16+l16, cols wv*32+quad*8 (16 B/lane): the exact bytes this wave's
  // O write will overwrite at the END of loop iteration nt (read-before-write
  // in-wave; column-disjoint across waves -> no barrier needed). ----
#pragma unroll
  for (int nt = 0; nt < 4; ++nt) {
    int ar = nt * 16 + l16; if (ar > 48) ar = 48;
    const unsigned short* ap = &xw[ar * 136 + quad * 8];
    uint4v qx;
#pragma unroll
    for (int ft = 0; ft < 2; ++ft) {
      const int wrow = wv * 32 + ft * 16 + l16;
      const unsigned short* wp = wbf + (wrow << 7) + quad * 8;
      const f32x4 bias = *(const f32x4*)(qkvb + wv * 32 + ft * 16 + quad * 4);
      f32x4 acc = {0.f, 0.f, 0.f, 0.f};
      acc = MFMA32(ld8(wp), ld8(ap), acc);
      acc = MFMA32(ld8(wp + 32), ld8(ap + 32), acc);
      acc = MFMA32(ld8(wp + 64), ld8(ap + 64), acc);
      acc = MFMA32(ld8(wp + 96), ld8(ap + 96), acc);
      qx[ft * 2 + 0] = pk2bf((acc[0] + bias[0]) * SCQ, (acc[1] + bias[1]) * SCQ);
      qx[ft * 2 + 1] = pk2bf((acc[2] + bias[2]) * SCQ, (acc[3] + bias[3]) * SCQ);
    }
    *(uint4v*)&ob[(nt * 16 + l16) * 136 + wv * 32 + quad * 8] = qx;
  }

  // ---- phase 4: per token-tile: load q (b128) -> S^T+softmax -> PV -> O ----
  {
    const float* bb = bias4 + ((((wy == 15) * 2 + (wx == 15)) * 4 + wv) << 12);
#pragma unroll
    for (int nt = 0; nt < 4; ++nt) {
      const uint4v qx = *(const uint4v*)&ob[(nt * 16 + l16) * 136 + wv * 32 + quad * 8];
      // S^T = K·Q^T + bias (mfma16), exp2 -> packed P (unnormalized; no
      // max-pass: |scores| small, exact invariance; 1/sum deferred)
      unsigned pf[4][2];
      float psum = 0.f;
#pragma unroll
      for (int mt = 0; mt < 4; ++mt) {
        f32x4 s = *(const f32x4*)(bb + ((((mt << 2) | nt) << 6) + lane) * 4);
        s = MFMA16(mk4(kbf[0][mt][0], kbf[0][mt][1]), mk4(qx[0], qx[1]), s);
        s = MFMA16(mk4(kbf[1][mt][0], kbf[1][mt][1]), mk4(qx[2], qx[3]), s);
        const float e0 = EXP2F(s[0]);
        const float e1 = EXP2F(s[1]);
        const float e2 = EXP2F(s[2]);
        const float e3 = EXP2F(s[3]);
        psum += (e0 + e1) + (e2 + e3);
        pf[mt][0] = pk2bf(e0, e1);
        pf[mt][1] = pk2bf(e2, e3);
      }
      psum += __shfl_xor(psum, 16);     // token's 64 keys live in 4 lanes
      psum += __shfl_xor(psum, 32);
      const float inv = 1.0f / psum;
      // O^T = V^T · P^T; 4 consecutive features -> 8B packed write to ob
      const int token = nt * 16 + l16;
#pragma unroll
      for (int dt = 0; dt < 2; ++dt) {
        f32x4 o = {0.f, 0.f, 0.f, 0.f};
#pragma unroll
        for (int mt = 0; mt < 4; ++mt)
          o = MFMA16(mk4(vbf[mt][dt][0], vbf[mt][dt][1]), mk4(pf[mt][0], pf[mt][1]), o);
        if (token < 49) {
          uint2v pkd;
          pkd.x = pk2bf(o[0] * inv, o[1] * inv);
          pkd.y = pk2bf(o[2] * inv, o[3] * inv);
          *(uint2v*)&ob[token * 136 + wv * 32 + dt * 16 + quad * 4] = pkd;
        }
      }
    }
  }
  __syncthreads();   // C: all heads' O ready; all xw reads done

  // ---- phase 5: proj swapped (out^T = Wp · O^T); stage into xw region ----
#pragma unroll
  for (int sub = 0; sub < 2; ++sub) {
    const int mtile = wv * 2 + sub;   // out-feature tile
    const unsigned short* wp = wbf + 49152 + ((mtile * 16 + l16) << 7) + quad * 8;
    const short8 wf0 = ld8(wp), wf1 = ld8(wp + 32), wf2 = ld8(wp + 64), wf3 = ld8(wp + 96);
    const f32x4 bias = *(const f32x4*)(projb + mtile * 16 + quad * 4);
#pragma unroll
    for (int nt = 0; nt < 4; ++nt) {
      int ar = nt * 16 + l16; if (ar > 48) ar = 48;
      const unsigned short* op = &ob[ar * 136 + quad * 8];
      f32x4 acc = {0.f, 0.f, 0.f, 0.f};
      acc = MFMA32(wf0, ld8(op), acc);
      acc = MFMA32(wf1, ld8(op + 32), acc);
      acc = MFMA32(wf2, ld8(op + 64), acc);
      acc = MFMA32(wf3, ld8(op + 96), acc);
      const int token = nt * 16 + l16;
      if (token < 49) {
        uint2v pkd;
        pkd.x = pk2bf(acc[0] + bias[0], acc[1] + bias[1]);
        pkd.y = pk2bf(acc[2] + bias[2], acc[3] + bias[3]);
        *(uint2v*)&xw[token * 136 + mtile * 16 + quad * 4] = pkd;
      }
    }
  }
  __syncthreads();   // E: staging ready

  // ---- phase 6: coalesced fp32 store (inverse roll == same index mapping) ----
  {
    const int c4 = t & 31, pr = t >> 5;
#pragma unroll
    for (int p = 0; p < 7; ++p) {
      const int n = p * 8 + pr;
      if (n < 49) {
        const int i = (n * 37) >> 8, j = n - i * 7;
        const int gi = (wy * 7 + i + 3) % 112;
        const int gj = (wx * 7 + j + 3) % 112;
        uint2v s = *(const uint2v*)&xw[n * 136 + c4 * 4];
        f32x4 v;
        v[0] = bf2f((unsigned short)(s.x & 0xFFFFu));
        v[1] = bf2f((unsigned short)(s.x >> 16));
        v[2] = bf2f((unsigned short)(s.y & 0xFFFFu));
        v[3] = bf2f((unsigned short)(s.y >> 16));
        *(f32x4*)(out + ((((long)b * 112 + gi) * 112 + gj) << 7) + c4 * 4) = v;
      }
    }
  }
}

extern "C" void kernel_launch(void* const* d_in, const int* in_sizes, int n_in,
                              void* d_out, int out_size, void* d_ws, size_t ws_size,
                              hipStream_t stream) {
  (void)in_sizes; (void)n_in; (void)out_size; (void)ws_size;
  const float* x     = (const float*)d_in[0];
  const float* qkvw  = (const float*)d_in[1];
  const float* qkvb  = (const float*)d_in[2];
  const float* projw = (const float*)d_in[3];
  const float* projb = (const float*)d_in[4];
  const float* tbl   = (const float*)d_in[5];
  float* outp = (float*)d_out;

  float*          ws_bias = (float*)d_ws;
  unsigned short* ws_w    = (unsigned short*)((char*)d_ws + WS_W_OFF);

  prep_kernel<<<128, 256, 0, stream>>>(qkvw, projw, tbl, ws_bias, ws_w);
  // main: 32 batches * 256 windows, 4 waves (1 per head) each
  swin_attn_kernel<<<8192, 256, 0, stream>>>(x, qkvb, projb, ws_bias, ws_w, outp);
}